// Round 12
// baseline (478.137 us; speedup 1.0000x reference)
//
#include <hip/hip_runtime.h>
#include <hip/hip_bf16.h>
#include <stdint.h>

// Problem constants (from reference)
#define N_NODES 100000
#define N_EDGES 1600000
#define D_NODE  32
#define D_EDGE  16
#define D_IN    48   // D_NODE + D_EDGE
#define D_HID   64
#define D_OUT   32

// coarse bucketing: bucket = dst >> 10 (1024 nodes/bucket)
#define NBKT 98        // ceil(100000/1024)
#define BCAP 18432     // slots/bucket (mean 16384, sigma~127 -> +16 sigma)
#define SLICES (BCAP / 256)   // 72 x 256-edge chunks per bucket
#define S1_EDGES 1024
#define S1_NB 1563     // ceil(1600000/1024)
#define SCAN_NB 391    // ceil(100000/256) -- prep grid

// agg grid: XCD-pinned (assumes round-robin blkid%8 -> XCD, bijective anyway)
#define CHUNKS_PER_BLOCK 4
#define BPB (SLICES / CHUNKS_PER_BLOCK)   // 18 blocks per bucket
#define MAXB_PER_XCD 13                   // ceil(NBKT/8)
#define AGG_GRID (8 * MAXB_PER_XCD * BPB) // 1872

// ---------------- workspace layout (bytes) ----------------
#define NFLAGS_OFF  ((size_t)0)          // 2 ints: {is_bf16, is_int64}
#define NB1_OFF     ((size_t)64)         // fp32 [64]
#define NB2_OFF     ((size_t)320)        // fp32 [32]
#define W1BF_OFF    ((size_t)1024)       // bf16 [n=64][k=64] n-major, k>=48 zero
#define W2BF_OFF    ((size_t)9216)       // bf16 [n=32][k=64] n-major
#define GCUR_OFF    ((size_t)16384)      // int [NBKT] absolute bucket cursors
#define XBF_OFF     ((size_t)65536)      // bf16 [N_NODES][32]           (6.4 MB)
#define TMPH_OFF    ((size_t)8388608)    // u32 [NBKT*BCAP] {src|rdst<<17} (7.2 MB)
#define TMPE_OFF    ((size_t)16777216)   // bf16 [NBKT*BCAP][16] payloads (57.8 MB)
#define REC_OFF     ((size_t)75497472)   // u64 [NBKT*BCAP] sorted records (14.5 MB)
#define ACCUM_OFF   ((size_t)90177536)   // f32 [N_NODES+1][32] accumulator (12.8 MB)

typedef __attribute__((ext_vector_type(8))) short bf16x8;   // 8 bf16 = 4 VGPRs
typedef __attribute__((ext_vector_type(4))) float f32x4;

__device__ inline float bf2f(unsigned int u16) {
    return __uint_as_float(u16 << 16);
}
__device__ inline unsigned short f2bf_rne(float f) {
    unsigned int x = __float_as_uint(f);
    unsigned int r = (x + 0x7FFFu + ((x >> 16) & 1u)) >> 16;
    return (unsigned short)r;
}
// packed RNE fp32x2 -> bf16x2 (v_cvt_pk_bf16_f32 on gfx950)
__device__ inline unsigned int pk_bf2(float a, float b) {
    float2 f; f.x = a; f.y = b;
    __hip_bfloat162 h = __float22bfloat162_rn(f);
    return *reinterpret_cast<unsigned int*>(&h);
}
__device__ inline float ld_f(const void* p, int i, int isbf) {
    if (isbf) return bf2f(((const unsigned short*)p)[i]);
    return ((const float*)p)[i];
}

// ---------------------------------------------------------------------------
// Prep: zero accum, init bucket cursors, build bf16 x copy (branch-free agg),
// detect dtypes (every block detects locally; block 0 publishes flags and
// builds bf16 n-major weights + fp32 biases).
// ---------------------------------------------------------------------------
__global__ __launch_bounds__(256) void prep_kernel(
        const void* __restrict__ xq, const void* __restrict__ idxq,
        const void* __restrict__ W1q, const void* __restrict__ b1q,
        const void* __restrict__ W2q, const void* __restrict__ b2q,
        char* __restrict__ ws) {
    const int t = threadIdx.x;
    const int i0 = blockIdx.x * 256 + t;

    __shared__ int s_isbf;
    if (t < 64) {   // every block: parallel dtype detection (L2-broadcast reads)
        unsigned short u = ((const unsigned short*)xq)[t];
        unsigned long long mb = __ballot(((u >> 7) & 0xFF) >= 140);
        if (t == 0) s_isbf = (mb == 0ULL);
    }

    // zero the output accumulator (incl. scratch row): (N_NODES+1)*32 floats
    float4* acc4 = (float4*)(ws + ACCUM_OFF);
    float4 z; z.x = z.y = z.z = z.w = 0.0f;
    for (int i = i0; i < (N_NODES + 1) * 32 / 4; i += SCAN_NB * 256) acc4[i] = z;

    __syncthreads();
    const int isbf = s_isbf;

    // bf16 x copy: 400000 chunks of 8 bf16 (16 B)
    unsigned short* xbf = (unsigned short*)(ws + XBF_OFF);
    for (int i = i0; i < N_NODES * 32 / 8; i += SCAN_NB * 256) {
        uint4 o;
        if (isbf) {
            o = ((const uint4*)xq)[i];
        } else {
            const float4* xp = (const float4*)xq + i * 2;
            float4 a = xp[0], b = xp[1];
            o.x = pk_bf2(a.x, a.y); o.y = pk_bf2(a.z, a.w);
            o.z = pk_bf2(b.x, b.y); o.w = pk_bf2(b.z, b.w);
        }
        ((uint4*)xbf)[i] = o;
    }

    if (blockIdx.x != 0) return;

    if (t < NBKT) ((int*)(ws + GCUR_OFF))[t] = t * BCAP;
    if (t < 64) {   // int64 detection (odd words of first 64 ints)
        int wodd = ((const int*)idxq)[2 * t + 1];
        unsigned long long mi = __ballot(wodd != 0);
        if (t == 0) {
            int* flags = (int*)(ws + NFLAGS_OFF);
            flags[0] = isbf;
            flags[1] = (mi == 0ULL);
        }
    }

    float* b1 = (float*)(ws + NB1_OFF);
    float* b2 = (float*)(ws + NB2_OFF);
    unsigned short* w1b = (unsigned short*)(ws + W1BF_OFF);
    unsigned short* w2b = (unsigned short*)(ws + W2BF_OFF);

    if (t < D_HID) b1[t] = ld_f(b1q, t, isbf);
    if (t < D_OUT) b2[t] = ld_f(b2q, t, isbf);

    // w1b[n][k] = W1[k][n] (k>=48 zero);  w2b[n][k] = W2[k][n]
    for (int i = t; i < D_HID * 64; i += 256) {
        int n = i >> 6, k = i & 63;
        float v = (k < D_IN) ? ld_f(W1q, k * D_HID + n, isbf) : 0.0f;
        w1b[i] = f2bf_rne(v);
    }
    for (int i = t; i < D_OUT * 64; i += 256) {
        int n = i >> 6, k = i & 63;
        w2b[i] = f2bf_rne(ld_f(W2q, k * D_OUT + n, isbf));
    }
}

// ---------------------------------------------------------------------------
// S1: coarse bucket partition with LDS-staged COALESCED writes.
// 512 THREADS per block, 1024 edges: same 44.5 KB LDS (3 blocks/CU) but
// 24 waves/CU -- 2x memory parallelism at identical traffic and run lengths.
// Payload read ONCE, streamed, staged in LDS, dumped in contiguous runs.
// ---------------------------------------------------------------------------
#define PIDX(s) ((s) + ((s) >> 3))
__global__ __launch_bounds__(512) void partition_kernel(
        const void* __restrict__ idxq, const void* __restrict__ eaq,
        char* __restrict__ ws) {
    const int is64 = ((const int*)(ws + NFLAGS_OFF))[1];
    const int isbf = ((const int*)(ws + NFLAGS_OFF))[0];
    __shared__ int hist[128];
    __shared__ int sc[128];
    __shared__ int lofs[128];
    __shared__ int base[128];
    __shared__ int lcur[128];
    __shared__ unsigned int hdr[S1_EDGES];
    __shared__ unsigned char bkt[S1_EDGES];
    __shared__ __align__(16) uint4 pay[2][S1_EDGES + (S1_EDGES >> 3)];

    const int t = threadIdx.x;
    if (t < 128) hist[t] = 0;
    __syncthreads();

    const int e0 = blockIdx.x * S1_EDGES;
    const int total = min(N_EDGES - e0, S1_EDGES);

    // pass 1: dst + histogram (2 edges/thread)
    int dstv[2];
#pragma unroll
    for (int i = 0; i < 2; ++i) {
        const int e = e0 + i * 512 + t;
        int dst = -1;
        if (e < N_EDGES) {
            if (is64) dst = (int)((const long long*)idxq)[e];
            else      dst = ((const int*)idxq)[e];
            atomicAdd(&hist[dst >> 10], 1);
        }
        dstv[i] = dst;
    }
    __syncthreads();

    // pass 2: 128-wide inclusive scan -> exclusive local offsets + global base
    if (t < 128) sc[t] = hist[t];
    __syncthreads();
    for (int d = 1; d < 128; d <<= 1) {
        int a = 0;
        if (t < 128 && t >= d) a = sc[t - d];
        __syncthreads();
        if (t < 128) sc[t] += a;
        __syncthreads();
    }
    if (t < 128) {
        lofs[t] = sc[t] - hist[t];
        lcur[t] = 0;
        if (t < NBKT) base[t] = atomicAdd((int*)(ws + GCUR_OFF) + t, hist[t]);
    }
    __syncthreads();

    // pass 3: stage into LDS at bucket-sorted local slots
#pragma unroll
    for (int i = 0; i < 2; ++i) {
        const int e = e0 + i * 512 + t;
        if (e >= N_EDGES) continue;
        const int dst = dstv[i];
        int src;
        if (is64) src = (int)((const long long*)idxq)[N_EDGES + e];
        else      src = ((const int*)idxq)[N_EDGES + e];
        const int b = dst >> 10;
        const int r = atomicAdd(&lcur[b], 1);
        const int s = lofs[b] + r;
        hdr[s] = (unsigned)src | ((unsigned)(dst & 1023) << 17);
        bkt[s] = (unsigned char)b;

        uint4 u0, u1;
        if (isbf) {
            const uint4* p = (const uint4*)((const unsigned short*)eaq + (size_t)e * 16);
            u0 = p[0]; u1 = p[1];
        } else {
            const float4* p = (const float4*)((const float*)eaq + (size_t)e * 16);
            float4 a = p[0], b4 = p[1], c = p[2], d = p[3];
            u0.x = pk_bf2(a.x, a.y);  u0.y = pk_bf2(a.z, a.w);
            u0.z = pk_bf2(b4.x, b4.y); u0.w = pk_bf2(b4.z, b4.w);
            u1.x = pk_bf2(c.x, c.y);  u1.y = pk_bf2(c.z, c.w);
            u1.z = pk_bf2(d.x, d.y);  u1.w = pk_bf2(d.z, d.w);
        }
        pay[0][PIDX(s)] = u0;
        pay[1][PIDX(s)] = u1;
    }
    __syncthreads();

    // pass 4: linear dump -> coalesced global runs
    unsigned int* tmph = (unsigned int*)(ws + TMPH_OFF);
    uint4*        tmp4 = (uint4*)(ws + TMPE_OFF);
    for (int s = t; s < total; s += 512) {
        const int b = bkt[s];
        const size_t g = (size_t)base[b] + (s - lofs[b]);
        tmph[g] = hdr[s];
        tmp4[g * 2]     = pay[0][PIDX(s)];
        tmp4[g * 2 + 1] = pay[1][PIDX(s)];
    }
}

// ---------------------------------------------------------------------------
// S2: bucket-local counting sort. One 1024-thread block per bucket: LDS
// histogram + LDS scan + scatter within the bucket's L2-resident rec window.
// Block b lands on XCD b%8 (round-robin) -- the same XCD the agg blocks for
// bucket b are pinned to, so rec stays dirty-in-L2 across kernels.
// rec = {src:17 | tix:15 | rdst:32hi}
// ---------------------------------------------------------------------------
__global__ __launch_bounds__(1024) void sort_kernel(char* __restrict__ ws) {
    __shared__ int hist[1024];
    __shared__ int cur[1024];
    const int b = blockIdx.x;
    const int t = threadIdx.x;
    hist[t] = 0;
    __syncthreads();

    const int cnt = ((const int*)(ws + GCUR_OFF))[b] - b * BCAP;
    const unsigned int* tmph = (const unsigned int*)(ws + TMPH_OFF) + (size_t)b * BCAP;
    unsigned long long* rec = (unsigned long long*)(ws + REC_OFF) + (size_t)b * BCAP;

    for (int i = t; i < cnt; i += 1024)
        atomicAdd(&hist[(tmph[i] >> 17) & 1023], 1);
    __syncthreads();

    // Hillis-Steele inclusive scan over 1024 -> exclusive cursors
    int v = hist[t];
    for (int d = 1; d < 1024; d <<= 1) {
        int a = (t >= d) ? hist[t - d] : 0;
        __syncthreads();
        hist[t] += a;
        __syncthreads();
    }
    cur[t] = hist[t] - v;
    __syncthreads();

    for (int i = t; i < cnt; i += 1024) {
        unsigned int h = tmph[i];
        const int rd = (h >> 17) & 1023;
        const int rk = atomicAdd(&cur[rd], 1);
        unsigned long long out = ((unsigned long long)rd << 32)
                               | ((unsigned long long)(unsigned)i << 17)
                               | (h & 0x1FFFFu);
        rec[rk] = out;
    }
}

// ---------------------------------------------------------------------------
// Fused edge-MLP + segment reduction, XCD-pinned, 2-STAGE SOFTWARE PIPELINE:
// while chunk cc computes (MFMA+LDS, no new vmem), chunk cc+1's rec loads and
// x/ea gathers are in flight. __launch_bounds__(256,4) caps VGPR at 128 so
// occupancy floors at 4 waves/SIMD.
// ---------------------------------------------------------------------------
__global__ __launch_bounds__(256, 4) void edge_mlp_agg_kernel(
        const char* __restrict__ wsro,
        float* __restrict__ accum) {
    const int xcd = blockIdx.x & 7;
    const int j   = blockIdx.x >> 3;          // [0, MAXB_PER_XCD*BPB)
    const int m   = j / BPB;
    const int nb  = 12 + (xcd < 2);           // buckets hosted on this XCD
    if (m >= nb) return;
    const int b      = xcd + (m << 3);
    const int slice0 = (j % BPB) * CHUNKS_PER_BLOCK;

    const int cnt = ((const int*)(wsro + GCUR_OFF))[b] - b * BCAP;
    if (slice0 * 256 >= cnt) return;
    const int nchunk = min(CHUNKS_PER_BLOCK, (cnt - slice0 * 256 + 255) >> 8);

    __shared__ __align__(16) unsigned short hbuf[4][2][16][72];

    const int w   = threadIdx.x >> 6;
    const int l   = threadIdx.x & 63;
    const int m16 = l & 15;
    const int q   = l >> 4;

    const unsigned short* w1b = (const unsigned short*)(wsro + W1BF_OFF);
    const unsigned short* w2b = (const unsigned short*)(wsro + W2BF_OFF);
    const float* b1 = (const float*)(wsro + NB1_OFF);
    const float* b2 = (const float*)(wsro + NB2_OFF);
    const unsigned short* xbf  = (const unsigned short*)(wsro + XBF_OFF);
    const unsigned short* tmpe = (const unsigned short*)(wsro + TMPE_OFF) + (size_t)b * BCAP * 16;
    const unsigned long long* rec = (const unsigned long long*)(wsro + REC_OFF) + (size_t)b * BCAP;

    // B-fragments: B[k=q*8+j][n=t*16+m16] = w?b[n][k] -> 16B loads (L1-hot)
    bf16x8 w1f[4][2], w2f[2][2];
#pragma unroll
    for (int t = 0; t < 4; ++t)
#pragma unroll
        for (int c = 0; c < 2; ++c)
            w1f[t][c] = *(const bf16x8*)(w1b + ((t * 16 + m16) * 64 + c * 32 + q * 8));
#pragma unroll
    for (int t = 0; t < 2; ++t)
#pragma unroll
        for (int c = 0; c < 2; ++c)
            w2f[t][c] = *(const bf16x8*)(w2b + ((t * 16 + m16) * 64 + c * 32 + q * 8));

    const float b1v[4] = { b1[m16], b1[16 + m16], b1[32 + m16], b1[48 + m16] };
    const float b2v[2] = { b2[m16], b2[16 + m16] };
    const int n0 = b << 10;

    // pipeline registers
    unsigned long long rnxt[4];
    int srcv[4], tixv[4], dstv[4];
    bf16x8 A0[4], A1[4], A0n[4], A1n[4];
    int srcn[4], tixn[4], dstn[4];

    // raw rec loads for chunk cc (always in-slab; dummies decoded later)
    auto LOADREC = [&](int cc, unsigned long long (&r)[4]) {
        const int kb = (slice0 + cc) * 256 + w * 64;
#pragma unroll
        for (int g = 0; g < 4; ++g)
            r[g] = rec[kb + g * 16 + m16];
    };
    // decode recs + issue x/ea gathers
    auto DECODE_GATHER = [&](int cc, unsigned long long (&r)[4],
                             int (&sv)[4], int (&tv)[4], int (&dv)[4],
                             bf16x8 (&a0)[4], bf16x8 (&a1)[4]) {
        const int kb = (slice0 + cc) * 256 + w * 64;
#pragma unroll
        for (int g = 0; g < 4; ++g) {
            const int p = kb + g * 16 + m16;
            if (p < cnt) {
                unsigned int lo = (unsigned int)r[g];
                sv[g] = (int)(lo & 0x1FFFFu);
                tv[g] = (int)(lo >> 17);
                dv[g] = n0 + (int)(r[g] >> 32);
            } else {
                sv[g] = 0; tv[g] = 0; dv[g] = N_NODES;
            }
        }
#pragma unroll
        for (int g = 0; g < 4; ++g) {
            a0[g] = *(const bf16x8*)(xbf  + (size_t)sv[g] * D_NODE + q * 8);
            a1[g] = *(const bf16x8*)(tmpe + (size_t)tv[g] * 16 + (q & 1) * 8);
        }
    };

    // layer 1 for tile g into buffer bb (current A0/A1)
    auto L1 = [&](int g, int bb) {
#pragma unroll
        for (int t = 0; t < 4; ++t) {
            f32x4 c;
            c[0] = c[1] = c[2] = c[3] = b1v[t];
            c = __builtin_amdgcn_mfma_f32_16x16x32_bf16(A0[g], w1f[t][0], c, 0, 0, 0);
            c = __builtin_amdgcn_mfma_f32_16x16x32_bf16(A1[g], w1f[t][1], c, 0, 0, 0);
            // C layout: row(m)=q*4+r, col(n)=t*16+m16
            unsigned int u0 = pk_bf2(fmaxf(c[0], 0.0f), fmaxf(c[1], 0.0f));
            unsigned int u1 = pk_bf2(fmaxf(c[2], 0.0f), fmaxf(c[3], 0.0f));
            hbuf[w][bb][q * 4 + 0][t * 16 + m16] = (unsigned short)u0;
            hbuf[w][bb][q * 4 + 1][t * 16 + m16] = (unsigned short)(u0 >> 16);
            hbuf[w][bb][q * 4 + 2][t * 16 + m16] = (unsigned short)u1;
            hbuf[w][bb][q * 4 + 3][t * 16 + m16] = (unsigned short)(u1 >> 16);
        }
    };

    // layer 2 + run-masked segment reduce + fp32 atomic flush for tile g
    auto L2R = [&](int g, int bb) {
        bf16x8 a20 = *(const bf16x8*)(&hbuf[w][bb][m16][q * 8]);
        bf16x8 a21 = *(const bf16x8*)(&hbuf[w][bb][m16][32 + q * 8]);
        f32x4 c0, c1;
        c0[0] = c0[1] = c0[2] = c0[3] = b2v[0];
        c1[0] = c1[1] = c1[2] = c1[3] = b2v[1];
        c0 = __builtin_amdgcn_mfma_f32_16x16x32_bf16(a20, w2f[0][0], c0, 0, 0, 0);
        c0 = __builtin_amdgcn_mfma_f32_16x16x32_bf16(a21, w2f[0][1], c0, 0, 0, 0);
        c1 = __builtin_amdgcn_mfma_f32_16x16x32_bf16(a20, w2f[1][0], c1, 0, 0, 0);
        c1 = __builtin_amdgcn_mfma_f32_16x16x32_bf16(a21, w2f[1][1], c1, 0, 0, 0);

        // runs of equal dst within the 16 sorted rows (identical in all 4
        // 16-lane subgroups -> wave-uniform loop, no divergence)
        const int dstw = dstv[g];
        int dprev = __shfl(dstw, (m16 + 15) & 15, 16);
        bool isStart = (m16 == 0) || (dprev != dstw);
        unsigned long long bal = __ballot(isStart);
        unsigned mask16 = (unsigned)(bal >> (l & 48)) & 0xFFFFu;
        int start = 0;
        while (start < 16) {
            unsigned rest = mask16 >> 1 >> start;       // bits for start+1..15
            int next = rest ? (start + 1 + (int)__builtin_ctz(rest)) : 16;
            int d = __shfl(dstw, start, 16);
            float s0 = 0.0f, s1 = 0.0f;
#pragma unroll
            for (int r = 0; r < 4; ++r) {
                int mm = q * 4 + r;                     // row = tile slot
                bool in = (mm >= start) && (mm < next);
                s0 += in ? c0[r] : 0.0f;
                s1 += in ? c1[r] : 0.0f;
            }
            // sum the 4 q-quads: lanes {l, l^16, l^32, l^48}
            s0 += __shfl_xor(s0, 16); s0 += __shfl_xor(s0, 32);
            s1 += __shfl_xor(s1, 16); s1 += __shfl_xor(s1, 32);
            if (q == 0) {
                unsafeAtomicAdd(accum + (size_t)d * 32 + m16,      s0);
                unsafeAtomicAdd(accum + (size_t)d * 32 + 16 + m16, s1);
            }
            start = next;
        }
    };

    // prologue: load chunk 0 fully
    LOADREC(0, rnxt);
    DECODE_GATHER(0, rnxt, srcv, tixv, dstv, A0, A1);

    for (int cc = 0; cc < nchunk; ++cc) {
        const bool hasNext = (cc + 1 < nchunk);
        if (hasNext) LOADREC(cc + 1, rnxt);          // rec loads in flight

        // compute phase 1 (MFMA + LDS only) hides rec latency
        L1(0, 0);
        L1(1, 1);
        L2R(0, 0);

        if (hasNext)                                  // gathers in flight
            DECODE_GATHER(cc + 1, rnxt, srcn, tixn, dstn, A0n, A1n);

        // compute phase 2 hides gather latency
        L1(2, 0);
        L2R(1, 1);
        L1(3, 1);
        L2R(2, 0);
        L2R(3, 1);

        if (hasNext) {                                // rotate pipeline regs
#pragma unroll
            for (int g = 0; g < 4; ++g) {
                A0[g] = A0n[g]; A1[g] = A1n[g];
                srcv[g] = srcn[g]; tixv[g] = tixn[g]; dstv[g] = dstn[g];
            }
        }
    }
}

// ---------------------------------------------------------------------------
// Convert the fp32 accumulator to the output dtype. 800000 float4 slots.
// ---------------------------------------------------------------------------
__global__ __launch_bounds__(256) void convert_kernel(
        const char* __restrict__ wsro, const float* __restrict__ accum,
        void* __restrict__ out) {
    const int isbf = ((const int*)(wsro + NFLAGS_OFF))[0];
    const int i = blockIdx.x * 256 + threadIdx.x;   // float4 index
    float4 v = ((const float4*)accum)[i];
    if (isbf) {
        uint2 u;
        u.x = pk_bf2(v.x, v.y);
        u.y = pk_bf2(v.z, v.w);
        ((uint2*)out)[i] = u;
    } else {
        ((float4*)out)[i] = v;
    }
}

extern "C" void kernel_launch(void* const* d_in, const int* in_sizes, int n_in,
                              void* d_out, int out_size, void* d_ws, size_t ws_size,
                              hipStream_t stream) {
    const void* x   = d_in[0];
    const void* idx = d_in[1];
    const void* ea  = d_in[2];
    const void* W1  = d_in[3];
    const void* b1  = d_in[4];
    const void* W2  = d_in[5];
    const void* b2  = d_in[6];
    char* ws = (char*)d_ws;

    hipLaunchKernelGGL(prep_kernel, dim3(SCAN_NB), dim3(256), 0, stream,
                       x, idx, W1, b1, W2, b2, ws);

    // coarse partition streaming idx + ea (-> bf16 payloads), LDS-staged,
    // 512-thread blocks for 2x wave occupancy at the same LDS footprint
    hipLaunchKernelGGL(partition_kernel, dim3(S1_NB), dim3(512), 0, stream, idx, ea, ws);

    // bucket-local counting sort (LDS histogram + scan, no global scan pass)
    hipLaunchKernelGGL(sort_kernel, dim3(NBKT), dim3(1024), 0, stream, ws);

    // XCD-pinned fused MLP + aggregation (2-stage pipelined)
    hipLaunchKernelGGL(edge_mlp_agg_kernel, dim3(AGG_GRID), dim3(256), 0, stream,
                       (const char*)ws, (float*)(ws + ACCUM_OFF));

    hipLaunchKernelGGL(convert_kernel, dim3(N_NODES * 32 / 4 / 256), dim3(256), 0, stream,
                       (const char*)ws, (const float*)(ws + ACCUM_OFF), d_out);
}

// Round 13
// 332.780 us; speedup vs baseline: 1.4368x; 1.4368x over previous
//
#include <hip/hip_runtime.h>
#include <hip/hip_bf16.h>
#include <stdint.h>

// Problem constants (from reference)
#define N_NODES 100000
#define N_EDGES 1600000
#define D_NODE  32
#define D_EDGE  16
#define D_IN    48   // D_NODE + D_EDGE
#define D_HID   64
#define D_OUT   32

// coarse bucketing: bucket = dst >> 10 (1024 nodes/bucket)
#define NBKT 98        // ceil(100000/1024)
#define BCAP 18432     // slots/bucket (mean 16384, sigma~127 -> +16 sigma)
#define SLICES (BCAP / 256)   // 72 x 256-edge chunks per bucket
#define S1_EDGES 1024
#define S1_NB 1563     // ceil(1600000/1024)
#define SCAN_NB 391    // ceil(100000/256) -- prep grid

// agg grid: XCD-pinned (assumes round-robin blkid%8 -> XCD, bijective anyway)
#define CHUNKS_PER_BLOCK 4
#define BPB (SLICES / CHUNKS_PER_BLOCK)   // 18 blocks per bucket
#define MAXB_PER_XCD 13                   // ceil(NBKT/8)
#define AGG_GRID (8 * MAXB_PER_XCD * BPB) // 1872

// ---------------- workspace layout (bytes) ----------------
#define NFLAGS_OFF  ((size_t)0)          // 2 ints: {is_bf16, is_int64}
#define NB1_OFF     ((size_t)64)         // fp32 [64]
#define NB2_OFF     ((size_t)320)        // fp32 [32]
#define W1BF_OFF    ((size_t)1024)       // bf16 [n=64][k=64] n-major, k>=48 zero
#define W2BF_OFF    ((size_t)9216)       // bf16 [n=32][k=64] n-major
#define GCUR_OFF    ((size_t)16384)      // int [NBKT] absolute bucket cursors
#define XBF_OFF     ((size_t)65536)      // bf16 [N_NODES][32]           (6.4 MB)
#define TMPH_OFF    ((size_t)8388608)    // u32 [NBKT*BCAP] {src|rdst<<17} (7.2 MB)
#define TMPE_OFF    ((size_t)16777216)   // bf16 [NBKT*BCAP][16] payloads (57.8 MB)
#define REC_OFF     ((size_t)75497472)   // u64 [NBKT*BCAP] sorted records (14.5 MB)
#define ACCUM_OFF   ((size_t)90177536)   // f32 [N_NODES+1][32] accumulator (12.8 MB)

typedef __attribute__((ext_vector_type(8))) short bf16x8;   // 8 bf16 = 4 VGPRs
typedef __attribute__((ext_vector_type(4))) float f32x4;

__device__ inline float bf2f(unsigned int u16) {
    return __uint_as_float(u16 << 16);
}
__device__ inline unsigned short f2bf_rne(float f) {
    unsigned int x = __float_as_uint(f);
    unsigned int r = (x + 0x7FFFu + ((x >> 16) & 1u)) >> 16;
    return (unsigned short)r;
}
// packed RNE fp32x2 -> bf16x2 (v_cvt_pk_bf16_f32 on gfx950)
__device__ inline unsigned int pk_bf2(float a, float b) {
    float2 f; f.x = a; f.y = b;
    __hip_bfloat162 h = __float22bfloat162_rn(f);
    return *reinterpret_cast<unsigned int*>(&h);
}
__device__ inline float ld_f(const void* p, int i, int isbf) {
    if (isbf) return bf2f(((const unsigned short*)p)[i]);
    return ((const float*)p)[i];
}

// ---------------------------------------------------------------------------
// Prep: zero accum, init bucket cursors, build bf16 x copy (branch-free agg),
// detect dtypes (every block detects locally; block 0 publishes flags and
// builds bf16 n-major weights + fp32 biases).
// ---------------------------------------------------------------------------
__global__ __launch_bounds__(256) void prep_kernel(
        const void* __restrict__ xq, const void* __restrict__ idxq,
        const void* __restrict__ W1q, const void* __restrict__ b1q,
        const void* __restrict__ W2q, const void* __restrict__ b2q,
        char* __restrict__ ws) {
    const int t = threadIdx.x;
    const int i0 = blockIdx.x * 256 + t;

    __shared__ int s_isbf;
    if (t < 64) {   // every block: parallel dtype detection (L2-broadcast reads)
        unsigned short u = ((const unsigned short*)xq)[t];
        unsigned long long mb = __ballot(((u >> 7) & 0xFF) >= 140);
        if (t == 0) s_isbf = (mb == 0ULL);
    }

    // zero the output accumulator (incl. scratch row): (N_NODES+1)*32 floats
    float4* acc4 = (float4*)(ws + ACCUM_OFF);
    float4 z; z.x = z.y = z.z = z.w = 0.0f;
    for (int i = i0; i < (N_NODES + 1) * 32 / 4; i += SCAN_NB * 256) acc4[i] = z;

    __syncthreads();
    const int isbf = s_isbf;

    // bf16 x copy: 400000 chunks of 8 bf16 (16 B)
    unsigned short* xbf = (unsigned short*)(ws + XBF_OFF);
    for (int i = i0; i < N_NODES * 32 / 8; i += SCAN_NB * 256) {
        uint4 o;
        if (isbf) {
            o = ((const uint4*)xq)[i];
        } else {
            const float4* xp = (const float4*)xq + i * 2;
            float4 a = xp[0], b = xp[1];
            o.x = pk_bf2(a.x, a.y); o.y = pk_bf2(a.z, a.w);
            o.z = pk_bf2(b.x, b.y); o.w = pk_bf2(b.z, b.w);
        }
        ((uint4*)xbf)[i] = o;
    }

    if (blockIdx.x != 0) return;

    if (t < NBKT) ((int*)(ws + GCUR_OFF))[t] = t * BCAP;
    if (t < 64) {   // int64 detection (odd words of first 64 ints)
        int wodd = ((const int*)idxq)[2 * t + 1];
        unsigned long long mi = __ballot(wodd != 0);
        if (t == 0) {
            int* flags = (int*)(ws + NFLAGS_OFF);
            flags[0] = isbf;
            flags[1] = (mi == 0ULL);
        }
    }

    float* b1 = (float*)(ws + NB1_OFF);
    float* b2 = (float*)(ws + NB2_OFF);
    unsigned short* w1b = (unsigned short*)(ws + W1BF_OFF);
    unsigned short* w2b = (unsigned short*)(ws + W2BF_OFF);

    if (t < D_HID) b1[t] = ld_f(b1q, t, isbf);
    if (t < D_OUT) b2[t] = ld_f(b2q, t, isbf);

    // w1b[n][k] = W1[k][n] (k>=48 zero);  w2b[n][k] = W2[k][n]
    for (int i = t; i < D_HID * 64; i += 256) {
        int n = i >> 6, k = i & 63;
        float v = (k < D_IN) ? ld_f(W1q, k * D_HID + n, isbf) : 0.0f;
        w1b[i] = f2bf_rne(v);
    }
    for (int i = t; i < D_OUT * 64; i += 256) {
        int n = i >> 6, k = i & 63;
        w2b[i] = f2bf_rne(ld_f(W2q, k * D_OUT + n, isbf));
    }
}

// ---------------------------------------------------------------------------
// S1: coarse bucket partition with LDS-staged COALESCED writes.
// 512 THREADS per block, 1024 edges: same 44.5 KB LDS (3 blocks/CU) but
// 24 waves/CU -- 2x memory parallelism at identical traffic and run lengths.
// Payload read ONCE, streamed, staged in LDS, dumped in contiguous runs.
// ---------------------------------------------------------------------------
#define PIDX(s) ((s) + ((s) >> 3))
__global__ __launch_bounds__(512) void partition_kernel(
        const void* __restrict__ idxq, const void* __restrict__ eaq,
        char* __restrict__ ws) {
    const int is64 = ((const int*)(ws + NFLAGS_OFF))[1];
    const int isbf = ((const int*)(ws + NFLAGS_OFF))[0];
    __shared__ int hist[128];
    __shared__ int sc[128];
    __shared__ int lofs[128];
    __shared__ int base[128];
    __shared__ int lcur[128];
    __shared__ unsigned int hdr[S1_EDGES];
    __shared__ unsigned char bkt[S1_EDGES];
    __shared__ __align__(16) uint4 pay[2][S1_EDGES + (S1_EDGES >> 3)];

    const int t = threadIdx.x;
    if (t < 128) hist[t] = 0;
    __syncthreads();

    const int e0 = blockIdx.x * S1_EDGES;
    const int total = min(N_EDGES - e0, S1_EDGES);

    // pass 1: dst + histogram (2 edges/thread)
    int dstv[2];
#pragma unroll
    for (int i = 0; i < 2; ++i) {
        const int e = e0 + i * 512 + t;
        int dst = -1;
        if (e < N_EDGES) {
            if (is64) dst = (int)((const long long*)idxq)[e];
            else      dst = ((const int*)idxq)[e];
            atomicAdd(&hist[dst >> 10], 1);
        }
        dstv[i] = dst;
    }
    __syncthreads();

    // pass 2: 128-wide inclusive scan -> exclusive local offsets + global base
    if (t < 128) sc[t] = hist[t];
    __syncthreads();
    for (int d = 1; d < 128; d <<= 1) {
        int a = 0;
        if (t < 128 && t >= d) a = sc[t - d];
        __syncthreads();
        if (t < 128) sc[t] += a;
        __syncthreads();
    }
    if (t < 128) {
        lofs[t] = sc[t] - hist[t];
        lcur[t] = 0;
        if (t < NBKT) base[t] = atomicAdd((int*)(ws + GCUR_OFF) + t, hist[t]);
    }
    __syncthreads();

    // pass 3: stage into LDS at bucket-sorted local slots
#pragma unroll
    for (int i = 0; i < 2; ++i) {
        const int e = e0 + i * 512 + t;
        if (e >= N_EDGES) continue;
        const int dst = dstv[i];
        int src;
        if (is64) src = (int)((const long long*)idxq)[N_EDGES + e];
        else      src = ((const int*)idxq)[N_EDGES + e];
        const int b = dst >> 10;
        const int r = atomicAdd(&lcur[b], 1);
        const int s = lofs[b] + r;
        hdr[s] = (unsigned)src | ((unsigned)(dst & 1023) << 17);
        bkt[s] = (unsigned char)b;

        uint4 u0, u1;
        if (isbf) {
            const uint4* p = (const uint4*)((const unsigned short*)eaq + (size_t)e * 16);
            u0 = p[0]; u1 = p[1];
        } else {
            const float4* p = (const float4*)((const float*)eaq + (size_t)e * 16);
            float4 a = p[0], b4 = p[1], c = p[2], d = p[3];
            u0.x = pk_bf2(a.x, a.y);  u0.y = pk_bf2(a.z, a.w);
            u0.z = pk_bf2(b4.x, b4.y); u0.w = pk_bf2(b4.z, b4.w);
            u1.x = pk_bf2(c.x, c.y);  u1.y = pk_bf2(c.z, c.w);
            u1.z = pk_bf2(d.x, d.y);  u1.w = pk_bf2(d.z, d.w);
        }
        pay[0][PIDX(s)] = u0;
        pay[1][PIDX(s)] = u1;
    }
    __syncthreads();

    // pass 4: linear dump -> coalesced global runs
    unsigned int* tmph = (unsigned int*)(ws + TMPH_OFF);
    uint4*        tmp4 = (uint4*)(ws + TMPE_OFF);
    for (int s = t; s < total; s += 512) {
        const int b = bkt[s];
        const size_t g = (size_t)base[b] + (s - lofs[b]);
        tmph[g] = hdr[s];
        tmp4[g * 2]     = pay[0][PIDX(s)];
        tmp4[g * 2 + 1] = pay[1][PIDX(s)];
    }
}

// ---------------------------------------------------------------------------
// S2: bucket-local counting sort. One 1024-thread block per bucket: LDS
// histogram + LDS scan + scatter within the bucket's L2-resident rec window.
// rec = {src:17 | tix:15 | rdst:32hi}
// ---------------------------------------------------------------------------
__global__ __launch_bounds__(1024) void sort_kernel(char* __restrict__ ws) {
    __shared__ int hist[1024];
    __shared__ int cur[1024];
    const int b = blockIdx.x;
    const int t = threadIdx.x;
    hist[t] = 0;
    __syncthreads();

    const int cnt = ((const int*)(ws + GCUR_OFF))[b] - b * BCAP;
    const unsigned int* tmph = (const unsigned int*)(ws + TMPH_OFF) + (size_t)b * BCAP;
    unsigned long long* rec = (unsigned long long*)(ws + REC_OFF) + (size_t)b * BCAP;

    for (int i = t; i < cnt; i += 1024)
        atomicAdd(&hist[(tmph[i] >> 17) & 1023], 1);
    __syncthreads();

    // Hillis-Steele inclusive scan over 1024 -> exclusive cursors
    int v = hist[t];
    for (int d = 1; d < 1024; d <<= 1) {
        int a = (t >= d) ? hist[t - d] : 0;
        __syncthreads();
        hist[t] += a;
        __syncthreads();
    }
    cur[t] = hist[t] - v;
    __syncthreads();

    for (int i = t; i < cnt; i += 1024) {
        unsigned int h = tmph[i];
        const int rd = (h >> 17) & 1023;
        const int rk = atomicAdd(&cur[rd], 1);
        unsigned long long out = ((unsigned long long)rd << 32)
                               | ((unsigned long long)(unsigned)i << 17)
                               | (h & 0x1FFFFu);
        rec[rk] = out;
    }
}

// ---------------------------------------------------------------------------
// Fused edge-MLP + segment reduction, XCD-pinned, 2-stage pipeline v2:
// pipeline state minimized to rn[4] + A0n/A1n (decode temps are transient,
// dst re-decoded from rn at rotation); NO min-waves clause so the allocator
// can use ~150 VGPR instead of spilling (round-12 lesson: the (256,4) cap
// forced ~315 MB/dispatch of scratch traffic).
// ---------------------------------------------------------------------------
__global__ __launch_bounds__(256) void edge_mlp_agg_kernel(
        const char* __restrict__ wsro,
        float* __restrict__ accum) {
    const int xcd = blockIdx.x & 7;
    const int j   = blockIdx.x >> 3;          // [0, MAXB_PER_XCD*BPB)
    const int m   = j / BPB;
    const int nb  = 12 + (xcd < 2);           // buckets hosted on this XCD
    if (m >= nb) return;
    const int b      = xcd + (m << 3);
    const int slice0 = (j % BPB) * CHUNKS_PER_BLOCK;

    const int cnt = ((const int*)(wsro + GCUR_OFF))[b] - b * BCAP;
    if (slice0 * 256 >= cnt) return;
    const int nchunk = min(CHUNKS_PER_BLOCK, (cnt - slice0 * 256 + 255) >> 8);

    __shared__ __align__(16) unsigned short hbuf[4][2][16][72];

    const int w   = threadIdx.x >> 6;
    const int l   = threadIdx.x & 63;
    const int m16 = l & 15;
    const int q   = l >> 4;

    const unsigned short* w1b = (const unsigned short*)(wsro + W1BF_OFF);
    const unsigned short* w2b = (const unsigned short*)(wsro + W2BF_OFF);
    const float* b1 = (const float*)(wsro + NB1_OFF);
    const float* b2 = (const float*)(wsro + NB2_OFF);
    const unsigned short* xbf  = (const unsigned short*)(wsro + XBF_OFF);
    const unsigned short* tmpe = (const unsigned short*)(wsro + TMPE_OFF) + (size_t)b * BCAP * 16;
    const unsigned long long* rec = (const unsigned long long*)(wsro + REC_OFF) + (size_t)b * BCAP;

    // B-fragments: B[k=q*8+j][n=t*16+m16] = w?b[n][k] -> 16B loads (L1-hot)
    bf16x8 w1f[4][2], w2f[2][2];
#pragma unroll
    for (int t = 0; t < 4; ++t)
#pragma unroll
        for (int c = 0; c < 2; ++c)
            w1f[t][c] = *(const bf16x8*)(w1b + ((t * 16 + m16) * 64 + c * 32 + q * 8));
#pragma unroll
    for (int t = 0; t < 2; ++t)
#pragma unroll
        for (int c = 0; c < 2; ++c)
            w2f[t][c] = *(const bf16x8*)(w2b + ((t * 16 + m16) * 64 + c * 32 + q * 8));

    const float b1v[4] = { b1[m16], b1[16 + m16], b1[32 + m16], b1[48 + m16] };
    const float b2v[2] = { b2[m16], b2[16 + m16] };
    const int n0 = b << 10;

    // pipeline state (kept minimal: 8 + 16 + 16 VGPR)
    int dstv[4];
    bf16x8 A0[4], A1[4];
    unsigned long long rn[4];
    bf16x8 A0n[4], A1n[4];

    // layer 1 for tile g into buffer bb (current A0/A1)
    auto L1 = [&](int g, int bb) {
#pragma unroll
        for (int t = 0; t < 4; ++t) {
            f32x4 c;
            c[0] = c[1] = c[2] = c[3] = b1v[t];
            c = __builtin_amdgcn_mfma_f32_16x16x32_bf16(A0[g], w1f[t][0], c, 0, 0, 0);
            c = __builtin_amdgcn_mfma_f32_16x16x32_bf16(A1[g], w1f[t][1], c, 0, 0, 0);
            // C layout: row(m)=q*4+r, col(n)=t*16+m16
            unsigned int u0 = pk_bf2(fmaxf(c[0], 0.0f), fmaxf(c[1], 0.0f));
            unsigned int u1 = pk_bf2(fmaxf(c[2], 0.0f), fmaxf(c[3], 0.0f));
            hbuf[w][bb][q * 4 + 0][t * 16 + m16] = (unsigned short)u0;
            hbuf[w][bb][q * 4 + 1][t * 16 + m16] = (unsigned short)(u0 >> 16);
            hbuf[w][bb][q * 4 + 2][t * 16 + m16] = (unsigned short)u1;
            hbuf[w][bb][q * 4 + 3][t * 16 + m16] = (unsigned short)(u1 >> 16);
        }
    };

    // layer 2 + run-masked segment reduce + fp32 atomic flush for tile g
    auto L2R = [&](int g, int bb) {
        bf16x8 a20 = *(const bf16x8*)(&hbuf[w][bb][m16][q * 8]);
        bf16x8 a21 = *(const bf16x8*)(&hbuf[w][bb][m16][32 + q * 8]);
        f32x4 c0, c1;
        c0[0] = c0[1] = c0[2] = c0[3] = b2v[0];
        c1[0] = c1[1] = c1[2] = c1[3] = b2v[1];
        c0 = __builtin_amdgcn_mfma_f32_16x16x32_bf16(a20, w2f[0][0], c0, 0, 0, 0);
        c0 = __builtin_amdgcn_mfma_f32_16x16x32_bf16(a21, w2f[0][1], c0, 0, 0, 0);
        c1 = __builtin_amdgcn_mfma_f32_16x16x32_bf16(a20, w2f[1][0], c1, 0, 0, 0);
        c1 = __builtin_amdgcn_mfma_f32_16x16x32_bf16(a21, w2f[1][1], c1, 0, 0, 0);

        // runs of equal dst within the 16 sorted rows (identical in all 4
        // 16-lane subgroups -> wave-uniform loop, no divergence)
        const int dstw = dstv[g];
        int dprev = __shfl(dstw, (m16 + 15) & 15, 16);
        bool isStart = (m16 == 0) || (dprev != dstw);
        unsigned long long bal = __ballot(isStart);
        unsigned mask16 = (unsigned)(bal >> (l & 48)) & 0xFFFFu;
        int start = 0;
        while (start < 16) {
            unsigned rest = mask16 >> 1 >> start;       // bits for start+1..15
            int next = rest ? (start + 1 + (int)__builtin_ctz(rest)) : 16;
            int d = __shfl(dstw, start, 16);
            float s0 = 0.0f, s1 = 0.0f;
#pragma unroll
            for (int r = 0; r < 4; ++r) {
                int mm = q * 4 + r;                     // row = tile slot
                bool in = (mm >= start) && (mm < next);
                s0 += in ? c0[r] : 0.0f;
                s1 += in ? c1[r] : 0.0f;
            }
            // sum the 4 q-quads: lanes {l, l^16, l^32, l^48}
            s0 += __shfl_xor(s0, 16); s0 += __shfl_xor(s0, 32);
            s1 += __shfl_xor(s1, 16); s1 += __shfl_xor(s1, 32);
            if (q == 0) {
                unsafeAtomicAdd(accum + (size_t)d * 32 + m16,      s0);
                unsafeAtomicAdd(accum + (size_t)d * 32 + 16 + m16, s1);
            }
            start = next;
        }
    };

    // prologue: chunk 0 loaded in-order (inlined, decode temps transient)
    {
        const int kb = slice0 * 256 + w * 64;
#pragma unroll
        for (int g = 0; g < 4; ++g) {
            const int p = kb + g * 16 + m16;
            unsigned long long r = rec[p];
            int sv = 0, tv = 0, dv = N_NODES;
            if (p < cnt) {
                unsigned int lo = (unsigned int)r;
                sv = (int)(lo & 0x1FFFFu);
                tv = (int)(lo >> 17);
                dv = n0 + (int)(r >> 32);
            }
            dstv[g] = dv;
            A0[g] = *(const bf16x8*)(xbf  + (size_t)sv * D_NODE + q * 8);
            A1[g] = *(const bf16x8*)(tmpe + (size_t)tv * 16 + (q & 1) * 8);
        }
    }

    for (int cc = 0; cc < nchunk; ++cc) {
        const bool hasNext = (cc + 1 < nchunk);
        const int kbn = (slice0 + cc + 1) * 256 + w * 64;

        if (hasNext) {                          // next-chunk rec loads in flight
#pragma unroll
            for (int g = 0; g < 4; ++g)
                rn[g] = rec[kbn + g * 16 + m16];
        }

        // compute phase 1 (MFMA + LDS only) hides rec latency
        L1(0, 0);
        L1(1, 1);
        L2R(0, 0);

        if (hasNext) {                          // next-chunk gathers in flight
#pragma unroll
            for (int g = 0; g < 4; ++g) {
                const int p = kbn + g * 16 + m16;
                unsigned int lo = (unsigned int)rn[g];
                int sv = (p < cnt) ? (int)(lo & 0x1FFFFu) : 0;
                int tv = (p < cnt) ? (int)(lo >> 17) : 0;
                A0n[g] = *(const bf16x8*)(xbf  + (size_t)sv * D_NODE + q * 8);
                A1n[g] = *(const bf16x8*)(tmpe + (size_t)tv * 16 + (q & 1) * 8);
            }
        }

        // compute phase 2 hides gather latency
        L1(2, 0);
        L2R(1, 1);
        L1(3, 1);
        L2R(2, 0);
        L2R(3, 1);

        if (hasNext) {                          // rotate (dst re-decoded from rn)
#pragma unroll
            for (int g = 0; g < 4; ++g) {
                const int p = kbn + g * 16 + m16;
                A0[g] = A0n[g];
                A1[g] = A1n[g];
                dstv[g] = (p < cnt) ? (n0 + (int)(rn[g] >> 32)) : N_NODES;
            }
        }
    }
}

// ---------------------------------------------------------------------------
// Convert the fp32 accumulator to the output dtype. 800000 float4 slots.
// ---------------------------------------------------------------------------
__global__ __launch_bounds__(256) void convert_kernel(
        const char* __restrict__ wsro, const float* __restrict__ accum,
        void* __restrict__ out) {
    const int isbf = ((const int*)(wsro + NFLAGS_OFF))[0];
    const int i = blockIdx.x * 256 + threadIdx.x;   // float4 index
    float4 v = ((const float4*)accum)[i];
    if (isbf) {
        uint2 u;
        u.x = pk_bf2(v.x, v.y);
        u.y = pk_bf2(v.z, v.w);
        ((uint2*)out)[i] = u;
    } else {
        ((float4*)out)[i] = v;
    }
}

extern "C" void kernel_launch(void* const* d_in, const int* in_sizes, int n_in,
                              void* d_out, int out_size, void* d_ws, size_t ws_size,
                              hipStream_t stream) {
    const void* x   = d_in[0];
    const void* idx = d_in[1];
    const void* ea  = d_in[2];
    const void* W1  = d_in[3];
    const void* b1  = d_in[4];
    const void* W2  = d_in[5];
    const void* b2  = d_in[6];
    char* ws = (char*)d_ws;

    hipLaunchKernelGGL(prep_kernel, dim3(SCAN_NB), dim3(256), 0, stream,
                       x, idx, W1, b1, W2, b2, ws);

    // coarse partition streaming idx + ea (-> bf16 payloads), LDS-staged,
    // 512-thread blocks for 2x wave occupancy at the same LDS footprint
    hipLaunchKernelGGL(partition_kernel, dim3(S1_NB), dim3(512), 0, stream, idx, ea, ws);

    // bucket-local counting sort (LDS histogram + scan, no global scan pass)
    hipLaunchKernelGGL(sort_kernel, dim3(NBKT), dim3(1024), 0, stream, ws);

    // XCD-pinned fused MLP + aggregation (2-stage pipelined, spill-free)
    hipLaunchKernelGGL(edge_mlp_agg_kernel, dim3(AGG_GRID), dim3(256), 0, stream,
                       (const char*)ws, (float*)(ws + ACCUM_OFF));

    hipLaunchKernelGGL(convert_kernel, dim3(N_NODES * 32 / 4 / 256), dim3(256), 0, stream,
                       (const char*)ws, (const float*)(ws + ACCUM_OFF), d_out);
}

// Round 14
// 323.058 us; speedup vs baseline: 1.4800x; 1.0301x over previous
//
#include <hip/hip_runtime.h>
#include <hip/hip_bf16.h>
#include <stdint.h>

// Problem constants (from reference)
#define N_NODES 100000
#define N_EDGES 1600000
#define D_NODE  32
#define D_EDGE  16
#define D_IN    48   // D_NODE + D_EDGE
#define D_HID   64
#define D_OUT   32

// coarse bucketing: bucket = dst >> 10 (1024 nodes/bucket)
#define NBKT 98        // ceil(100000/1024)
#define BCAP 18432     // slots/bucket (mean 16384, sigma~127 -> +16 sigma)
#define SLICES (BCAP / 256)   // 72 x 256-edge chunks per bucket
#define S1_EDGES 1024
#define S1_NB 1563     // ceil(1600000/1024)

// agg grid: XCD-pinned (assumes round-robin blkid%8 -> XCD, bijective anyway)
#define CHUNKS_PER_BLOCK 4
#define BPB (SLICES / CHUNKS_PER_BLOCK)   // 18 blocks per bucket
#define MAXB_PER_XCD 13                   // ceil(NBKT/8)
#define AGG_GRID (8 * MAXB_PER_XCD * BPB) // 1872

// ---------------- workspace layout (bytes) ----------------
#define NFLAGS_OFF  ((size_t)0)          // 2 ints: {is_bf16, is_int64}
#define NB1_OFF     ((size_t)64)         // fp32 [64]
#define NB2_OFF     ((size_t)320)        // fp32 [32]
#define W1BF_OFF    ((size_t)1024)       // bf16 [n=64][k=64] n-major, k>=48 zero
#define W2BF_OFF    ((size_t)9216)       // bf16 [n=32][k=64] n-major
#define GCUR_OFF    ((size_t)16384)      // int [NBKT] RELATIVE bucket cursors (memset 0)
#define XBF_OFF     ((size_t)65536)      // bf16 [N_NODES][32]           (6.4 MB)
#define TMPH_OFF    ((size_t)8388608)    // u32 [NBKT*BCAP] {src|rdst<<17} (7.2 MB)
#define TMPE_OFF    ((size_t)16777216)   // bf16 [NBKT*BCAP][16] payloads (57.8 MB)
#define REC_OFF     ((size_t)75497472)   // u64 [NBKT*BCAP] sorted records (14.5 MB)
#define ACCUM_OFF   ((size_t)90177536)   // f32 [N_NODES+1][32] accumulator (12.8 MB)

typedef __attribute__((ext_vector_type(8))) short bf16x8;   // 8 bf16 = 4 VGPRs
typedef __attribute__((ext_vector_type(4))) float f32x4;

__device__ inline float bf2f(unsigned int u16) {
    return __uint_as_float(u16 << 16);
}
__device__ inline unsigned short f2bf_rne(float f) {
    unsigned int x = __float_as_uint(f);
    unsigned int r = (x + 0x7FFFu + ((x >> 16) & 1u)) >> 16;
    return (unsigned short)r;
}
// packed RNE fp32x2 -> bf16x2 (v_cvt_pk_bf16_f32 on gfx950)
__device__ inline unsigned int pk_bf2(float a, float b) {
    float2 f; f.x = a; f.y = b;
    __hip_bfloat162 h = __float22bfloat162_rn(f);
    return *reinterpret_cast<unsigned int*>(&h);
}
__device__ inline float ld_f(const void* p, int i, int isbf) {
    if (isbf) return bf2f(((const unsigned short*)p)[i]);
    return ((const float*)p)[i];
}

// ---------------------------------------------------------------------------
// S1: coarse bucket partition with LDS-staged COALESCED writes, now ALSO
// absorbing prep's streaming work (accum zero, xbf build) and detecting
// dtypes locally per block (64-lane ballots on L2-broadcast reads).
// 512 threads = 1024 edges; 44.5 KB LDS; payload read ONCE, staged in LDS,
// dumped in contiguous runs. Cursors are bucket-RELATIVE (memset-0 before).
// ---------------------------------------------------------------------------
#define PIDX(s) ((s) + ((s) >> 3))
__global__ __launch_bounds__(512) void partition_kernel(
        const void* __restrict__ idxq, const void* __restrict__ eaq,
        const void* __restrict__ xq, char* __restrict__ ws) {
    __shared__ int s_flags;
    __shared__ int hist[128];
    __shared__ int sc[128];
    __shared__ int lofs[128];
    __shared__ int base[128];
    __shared__ int lcur[128];
    __shared__ unsigned int hdr[S1_EDGES];
    __shared__ unsigned char bkt[S1_EDGES];
    __shared__ __align__(16) uint4 pay[2][S1_EDGES + (S1_EDGES >> 3)];

    const int t = threadIdx.x;
    const int i0 = blockIdx.x * 512 + t;

    if (t < 64) {   // local dtype detection
        unsigned short u = ((const unsigned short*)xq)[t];
        unsigned long long mb = __ballot(((u >> 7) & 0xFF) >= 140);
        int wodd = ((const int*)idxq)[2 * t + 1];
        unsigned long long mi = __ballot(wodd != 0);
        if (t == 0) s_flags = (mb == 0ULL ? 1 : 0) | (mi == 0ULL ? 2 : 0);
    }
    if (t < 128) hist[t] = 0;

    // absorb prep: zero accum (incl. scratch row N_NODES)
    {
        float4* acc4 = (float4*)(ws + ACCUM_OFF);
        float4 z; z.x = z.y = z.z = z.w = 0.0f;
        for (int i = i0; i < (N_NODES + 1) * 32 / 4; i += S1_NB * 512) acc4[i] = z;
    }
    __syncthreads();
    const int isbf = s_flags & 1;
    const int is64 = (s_flags >> 1) & 1;

    // absorb prep: bf16 x copy (400000 chunks of 8 bf16)
    {
        unsigned short* xbf = (unsigned short*)(ws + XBF_OFF);
        for (int i = i0; i < N_NODES * 32 / 8; i += S1_NB * 512) {
            uint4 o;
            if (isbf) {
                o = ((const uint4*)xq)[i];
            } else {
                const float4* xp = (const float4*)xq + i * 2;
                float4 a = xp[0], b = xp[1];
                o.x = pk_bf2(a.x, a.y); o.y = pk_bf2(a.z, a.w);
                o.z = pk_bf2(b.x, b.y); o.w = pk_bf2(b.z, b.w);
            }
            ((uint4*)xbf)[i] = o;
        }
    }

    const int e0 = blockIdx.x * S1_EDGES;
    const int total = min(N_EDGES - e0, S1_EDGES);

    // pass 1: dst + histogram (2 edges/thread)
    int dstv[2];
#pragma unroll
    for (int i = 0; i < 2; ++i) {
        const int e = e0 + i * 512 + t;
        int dst = -1;
        if (e < N_EDGES) {
            if (is64) dst = (int)((const long long*)idxq)[e];
            else      dst = ((const int*)idxq)[e];
            atomicAdd(&hist[dst >> 10], 1);
        }
        dstv[i] = dst;
    }
    __syncthreads();

    // pass 2: 128-wide inclusive scan -> exclusive local offsets + global base
    if (t < 128) sc[t] = hist[t];
    __syncthreads();
    for (int d = 1; d < 128; d <<= 1) {
        int a = 0;
        if (t < 128 && t >= d) a = sc[t - d];
        __syncthreads();
        if (t < 128) sc[t] += a;
        __syncthreads();
    }
    if (t < 128) {
        lofs[t] = sc[t] - hist[t];
        lcur[t] = 0;
        if (t < NBKT)
            base[t] = t * BCAP + atomicAdd((int*)(ws + GCUR_OFF) + t, hist[t]);
    }
    __syncthreads();

    // pass 3: stage into LDS at bucket-sorted local slots
#pragma unroll
    for (int i = 0; i < 2; ++i) {
        const int e = e0 + i * 512 + t;
        if (e >= N_EDGES) continue;
        const int dst = dstv[i];
        int src;
        if (is64) src = (int)((const long long*)idxq)[N_EDGES + e];
        else      src = ((const int*)idxq)[N_EDGES + e];
        const int b = dst >> 10;
        const int r = atomicAdd(&lcur[b], 1);
        const int s = lofs[b] + r;
        hdr[s] = (unsigned)src | ((unsigned)(dst & 1023) << 17);
        bkt[s] = (unsigned char)b;

        uint4 u0, u1;
        if (isbf) {
            const uint4* p = (const uint4*)((const unsigned short*)eaq + (size_t)e * 16);
            u0 = p[0]; u1 = p[1];
        } else {
            const float4* p = (const float4*)((const float*)eaq + (size_t)e * 16);
            float4 a = p[0], b4 = p[1], c = p[2], d = p[3];
            u0.x = pk_bf2(a.x, a.y);  u0.y = pk_bf2(a.z, a.w);
            u0.z = pk_bf2(b4.x, b4.y); u0.w = pk_bf2(b4.z, b4.w);
            u1.x = pk_bf2(c.x, c.y);  u1.y = pk_bf2(c.z, c.w);
            u1.z = pk_bf2(d.x, d.y);  u1.w = pk_bf2(d.z, d.w);
        }
        pay[0][PIDX(s)] = u0;
        pay[1][PIDX(s)] = u1;
    }
    __syncthreads();

    // pass 4: linear dump -> coalesced global runs
    unsigned int* tmph = (unsigned int*)(ws + TMPH_OFF);
    uint4*        tmp4 = (uint4*)(ws + TMPE_OFF);
    for (int s = t; s < total; s += 512) {
        const int b = bkt[s];
        const size_t g = (size_t)(b * BCAP) + base[b] - b * BCAP + (s - lofs[b]);
        tmph[(size_t)base[b] + (s - lofs[b])] = hdr[s];
        tmp4[((size_t)base[b] + (s - lofs[b])) * 2]     = pay[0][PIDX(s)];
        tmp4[((size_t)base[b] + (s - lofs[b])) * 2 + 1] = pay[1][PIDX(s)];
        (void)g;
    }
}

// ---------------------------------------------------------------------------
// S2: bucket-local counting sort (blocks 0..97) + weight prep (block 98,
// absorbs prep's weight/bias conversion and publishes the isbf flag that
// convert_kernel reads). rec = {src:17 | tix:15 | rdst:32hi}
// ---------------------------------------------------------------------------
__global__ __launch_bounds__(1024) void sort_kernel(
        const void* __restrict__ xq,
        const void* __restrict__ W1q, const void* __restrict__ b1q,
        const void* __restrict__ W2q, const void* __restrict__ b2q,
        char* __restrict__ ws) {
    const int b = blockIdx.x;
    const int t = threadIdx.x;

    if (b == NBKT) {   // weight-prep block
        __shared__ int s_isbf;
        if (t < 64) {
            unsigned short u = ((const unsigned short*)xq)[t];
            unsigned long long mb = __ballot(((u >> 7) & 0xFF) >= 140);
            if (t == 0) s_isbf = (mb == 0ULL);
        }
        __syncthreads();
        const int isbf = s_isbf;
        if (t == 0) ((int*)(ws + NFLAGS_OFF))[0] = isbf;

        float* b1 = (float*)(ws + NB1_OFF);
        float* b2 = (float*)(ws + NB2_OFF);
        unsigned short* w1b = (unsigned short*)(ws + W1BF_OFF);
        unsigned short* w2b = (unsigned short*)(ws + W2BF_OFF);
        if (t < D_HID) b1[t] = ld_f(b1q, t, isbf);
        if (t < D_OUT) b2[t] = ld_f(b2q, t, isbf);
        for (int i = t; i < D_HID * 64; i += 1024) {
            int n = i >> 6, k = i & 63;
            float v = (k < D_IN) ? ld_f(W1q, k * D_HID + n, isbf) : 0.0f;
            w1b[i] = f2bf_rne(v);
        }
        for (int i = t; i < D_OUT * 64; i += 1024) {
            int n = i >> 6, k = i & 63;
            w2b[i] = f2bf_rne(ld_f(W2q, k * D_OUT + n, isbf));
        }
        return;
    }

    __shared__ int hist[1024];
    __shared__ int cur[1024];
    hist[t] = 0;
    __syncthreads();

    const int cnt = ((const int*)(ws + GCUR_OFF))[b];   // relative count
    const unsigned int* tmph = (const unsigned int*)(ws + TMPH_OFF) + (size_t)b * BCAP;
    unsigned long long* rec = (unsigned long long*)(ws + REC_OFF) + (size_t)b * BCAP;

    for (int i = t; i < cnt; i += 1024)
        atomicAdd(&hist[(tmph[i] >> 17) & 1023], 1);
    __syncthreads();

    // Hillis-Steele inclusive scan over 1024 -> exclusive cursors
    int v = hist[t];
    for (int d = 1; d < 1024; d <<= 1) {
        int a = (t >= d) ? hist[t - d] : 0;
        __syncthreads();
        hist[t] += a;
        __syncthreads();
    }
    cur[t] = hist[t] - v;
    __syncthreads();

    for (int i = t; i < cnt; i += 1024) {
        unsigned int h = tmph[i];
        const int rd = (h >> 17) & 1023;
        const int rk = atomicAdd(&cur[rd], 1);
        unsigned long long out = ((unsigned long long)rd << 32)
                               | ((unsigned long long)(unsigned)i << 17)
                               | (h & 0x1FFFFu);
        rec[rk] = out;
    }
}

// ---------------------------------------------------------------------------
// Fused edge-MLP + segment reduction over bucket-sorted edges.
// ROUND-10 BODY (proven 85.5 us): XCD-pinned flat grid, CHUNKS_PER_BLOCK
// chunks per block, 4 independent waves, NO software pipeline (rounds 12/13
// showed pipeline VGPR cost > ILP gain on this gather-bound kernel).
// ---------------------------------------------------------------------------
__global__ __launch_bounds__(256) void edge_mlp_agg_kernel(
        const char* __restrict__ wsro,
        float* __restrict__ accum) {
    const int xcd = blockIdx.x & 7;
    const int j   = blockIdx.x >> 3;          // [0, MAXB_PER_XCD*BPB)
    const int m   = j / BPB;
    const int nb  = 12 + (xcd < 2);           // buckets hosted on this XCD
    if (m >= nb) return;
    const int b      = xcd + (m << 3);
    const int slice0 = (j % BPB) * CHUNKS_PER_BLOCK;

    const int cnt = ((const int*)(wsro + GCUR_OFF))[b];   // relative count
    if (slice0 * 256 >= cnt) return;

    __shared__ __align__(16) unsigned short hbuf[4][2][16][72];

    const int w   = threadIdx.x >> 6;
    const int l   = threadIdx.x & 63;
    const int m16 = l & 15;
    const int q   = l >> 4;

    const unsigned short* w1b = (const unsigned short*)(wsro + W1BF_OFF);
    const unsigned short* w2b = (const unsigned short*)(wsro + W2BF_OFF);
    const float* b1 = (const float*)(wsro + NB1_OFF);
    const float* b2 = (const float*)(wsro + NB2_OFF);
    const unsigned short* xbf  = (const unsigned short*)(wsro + XBF_OFF);
    const unsigned short* tmpe = (const unsigned short*)(wsro + TMPE_OFF) + (size_t)b * BCAP * 16;
    const unsigned long long* rec = (const unsigned long long*)(wsro + REC_OFF) + (size_t)b * BCAP;

    // B-fragments: B[k=q*8+j][n=t*16+m16] = w?b[n][k] -> 16B loads (L1-hot)
    bf16x8 w1f[4][2], w2f[2][2];
#pragma unroll
    for (int t = 0; t < 4; ++t)
#pragma unroll
        for (int c = 0; c < 2; ++c)
            w1f[t][c] = *(const bf16x8*)(w1b + ((t * 16 + m16) * 64 + c * 32 + q * 8));
#pragma unroll
    for (int t = 0; t < 2; ++t)
#pragma unroll
        for (int c = 0; c < 2; ++c)
            w2f[t][c] = *(const bf16x8*)(w2b + ((t * 16 + m16) * 64 + c * 32 + q * 8));

    const float b1v[4] = { b1[m16], b1[16 + m16], b1[32 + m16], b1[48 + m16] };
    const float b2v[2] = { b2[m16], b2[16 + m16] };
    const int n0 = b << 10;

    for (int cc = 0; cc < CHUNKS_PER_BLOCK; ++cc) {
        const int kb = (slice0 + cc) * 256 + w * 64;
        if ((slice0 + cc) * 256 >= cnt) break;

        // sorted records for all 4 tiles (issued up front)
        int srcv[4], tixv[4], dstv[4];
#pragma unroll
        for (int g = 0; g < 4; ++g) {
            const int p = kb + g * 16 + m16;
            unsigned long long r = rec[p];          // always within the BCAP slab
            if (p < cnt) {
                unsigned int lo = (unsigned int)r;
                srcv[g] = (int)(lo & 0x1FFFFu);
                tixv[g] = (int)(lo >> 17);
                dstv[g] = n0 + (int)(r >> 32);
            } else {                                // dummy edge -> scratch row
                srcv[g] = 0;
                tixv[g] = 0;
                dstv[g] = N_NODES;
            }
        }

        // input fragments for all 4 tiles (max memory parallelism, branch-free)
        bf16x8 A0[4], A1[4];
#pragma unroll
        for (int g = 0; g < 4; ++g) {
            A0[g] = *(const bf16x8*)(xbf  + (size_t)srcv[g] * D_NODE + q * 8);
            A1[g] = *(const bf16x8*)(tmpe + (size_t)tixv[g] * 16 + (q & 1) * 8);
        }

        // layer 1 for tile g into buffer bb
        auto L1 = [&](int g, int bb) {
#pragma unroll
            for (int t = 0; t < 4; ++t) {
                f32x4 c;
                c[0] = c[1] = c[2] = c[3] = b1v[t];
                c = __builtin_amdgcn_mfma_f32_16x16x32_bf16(A0[g], w1f[t][0], c, 0, 0, 0);
                c = __builtin_amdgcn_mfma_f32_16x16x32_bf16(A1[g], w1f[t][1], c, 0, 0, 0);
                // C layout: row(m)=q*4+r, col(n)=t*16+m16
                unsigned int u0 = pk_bf2(fmaxf(c[0], 0.0f), fmaxf(c[1], 0.0f));
                unsigned int u1 = pk_bf2(fmaxf(c[2], 0.0f), fmaxf(c[3], 0.0f));
                hbuf[w][bb][q * 4 + 0][t * 16 + m16] = (unsigned short)u0;
                hbuf[w][bb][q * 4 + 1][t * 16 + m16] = (unsigned short)(u0 >> 16);
                hbuf[w][bb][q * 4 + 2][t * 16 + m16] = (unsigned short)u1;
                hbuf[w][bb][q * 4 + 3][t * 16 + m16] = (unsigned short)(u1 >> 16);
            }
        };

        // layer 2 + run-masked segment reduce + fp32 atomic flush for tile g
        auto L2R = [&](int g, int bb) {
            bf16x8 a20 = *(const bf16x8*)(&hbuf[w][bb][m16][q * 8]);
            bf16x8 a21 = *(const bf16x8*)(&hbuf[w][bb][m16][32 + q * 8]);
            f32x4 c0, c1;
            c0[0] = c0[1] = c0[2] = c0[3] = b2v[0];
            c1[0] = c1[1] = c1[2] = c1[3] = b2v[1];
            c0 = __builtin_amdgcn_mfma_f32_16x16x32_bf16(a20, w2f[0][0], c0, 0, 0, 0);
            c0 = __builtin_amdgcn_mfma_f32_16x16x32_bf16(a21, w2f[0][1], c0, 0, 0, 0);
            c1 = __builtin_amdgcn_mfma_f32_16x16x32_bf16(a20, w2f[1][0], c1, 0, 0, 0);
            c1 = __builtin_amdgcn_mfma_f32_16x16x32_bf16(a21, w2f[1][1], c1, 0, 0, 0);

            // runs of equal dst within the 16 sorted rows (identical in all 4
            // 16-lane subgroups -> wave-uniform loop, no divergence)
            const int dstw = dstv[g];
            int dprev = __shfl(dstw, (m16 + 15) & 15, 16);
            bool isStart = (m16 == 0) || (dprev != dstw);
            unsigned long long bal = __ballot(isStart);
            unsigned mask16 = (unsigned)(bal >> (l & 48)) & 0xFFFFu;
            int start = 0;
            while (start < 16) {
                unsigned rest = mask16 >> 1 >> start;   // bits for start+1..15
                int next = rest ? (start + 1 + (int)__builtin_ctz(rest)) : 16;
                int d = __shfl(dstw, start, 16);
                float s0 = 0.0f, s1 = 0.0f;
#pragma unroll
                for (int r = 0; r < 4; ++r) {
                    int mm = q * 4 + r;                 // row = tile slot
                    bool in = (mm >= start) && (mm < next);
                    s0 += in ? c0[r] : 0.0f;
                    s1 += in ? c1[r] : 0.0f;
                }
                // sum the 4 q-quads: lanes {l, l^16, l^32, l^48}
                s0 += __shfl_xor(s0, 16); s0 += __shfl_xor(s0, 32);
                s1 += __shfl_xor(s1, 16); s1 += __shfl_xor(s1, 32);
                if (q == 0) {
                    unsafeAtomicAdd(accum + (size_t)d * 32 + m16,      s0);
                    unsafeAtomicAdd(accum + (size_t)d * 32 + 16 + m16, s1);
                }
                start = next;
            }
        };

        // software pipeline over 2 buffers; per-wave DS ordering = sync-free
        L1(0, 0);
        L1(1, 1);
        L2R(0, 0);
        L1(2, 0);
        L2R(1, 1);
        L1(3, 1);
        L2R(2, 0);
        L2R(3, 1);
    }
}

// ---------------------------------------------------------------------------
// Convert the fp32 accumulator to the output dtype. 800000 float4 slots.
// ---------------------------------------------------------------------------
__global__ __launch_bounds__(256) void convert_kernel(
        const char* __restrict__ wsro, const float* __restrict__ accum,
        void* __restrict__ out) {
    const int isbf = ((const int*)(wsro + NFLAGS_OFF))[0];
    const int i = blockIdx.x * 256 + threadIdx.x;   // float4 index
    float4 v = ((const float4*)accum)[i];
    if (isbf) {
        uint2 u;
        u.x = pk_bf2(v.x, v.y);
        u.y = pk_bf2(v.z, v.w);
        ((uint2*)out)[i] = u;
    } else {
        ((float4*)out)[i] = v;
    }
}

extern "C" void kernel_launch(void* const* d_in, const int* in_sizes, int n_in,
                              void* d_out, int out_size, void* d_ws, size_t ws_size,
                              hipStream_t stream) {
    const void* x   = d_in[0];
    const void* idx = d_in[1];
    const void* ea  = d_in[2];
    const void* W1  = d_in[3];
    const void* b1  = d_in[4];
    const void* W2  = d_in[5];
    const void* b2  = d_in[6];
    char* ws = (char*)d_ws;

    // bucket cursors (relative) -> zero
    hipMemsetAsync(ws + GCUR_OFF, 0, NBKT * sizeof(int), stream);

    // partition (absorbs prep: dtype detect, accum zero, xbf build)
    hipLaunchKernelGGL(partition_kernel, dim3(S1_NB), dim3(512), 0, stream,
                       idx, ea, x, ws);

    // bucket-local counting sort + weight-prep block
    hipLaunchKernelGGL(sort_kernel, dim3(NBKT + 1), dim3(1024), 0, stream,
                       x, W1, b1, W2, b2, ws);

    // XCD-pinned fused MLP + aggregation (round-10 body)
    hipLaunchKernelGGL(edge_mlp_agg_kernel, dim3(AGG_GRID), dim3(256), 0, stream,
                       (const char*)ws, (float*)(ws + ACCUM_OFF));

    hipLaunchKernelGGL(convert_kernel, dim3(N_NODES * 32 / 4 / 256), dim3(256), 0, stream,
                       (const char*)ws, (const float*)(ws + ACCUM_OFF), d_out);
}